// Round 14
// baseline (78.014 us; speedup 1.0000x reference)
//
#include <hip/hip_runtime.h>

#define NCAP 10     // capsule classes c
#define NB   256    // batch b
#define NN   1152   // route nodes n
#define KI   8      // input dim i
#define NO   16     // output dim o
#define NT   1024   // threads per block (16 waves)
#define NWV  16
#define TB   2      // batches per block
#define NITER 3

typedef float v2f __attribute__((ext_vector_type(2)));

// Round-13 baseline (58.5 us, 72% occ, VGPR 32, no spill) + ONE change:
// packed-f32 math (v_pk_fma_f32 via ext_vector float2 fma). Build packs the
// TB dim into v2f accumulators (32 pk vs 64 scalar FMA/round); routing packs
// the o-pairs (16 pk vs 32 scalar FMA per n,tb). Layout/barriers unchanged.
__global__ __launch_bounds__(NT, 8) void capsule_kernel(
    const float* __restrict__ x,    // [256,1152,8]
    const float* __restrict__ w,    // [10,1152,8,16]
    float* __restrict__ out)        // [10,256,16]
{
    __shared__ unsigned s_pr[TB * NN * 8];    // 72 KB bf16-pair priors
    __shared__ float s_red2[NWV][TB][NO];     // per-wave comp partials
    __shared__ float s_ls[NWV][TB];           // per-wave exp-sum partials
    __shared__ float s_v[TB][NO];             // squashed v broadcast

    const int t    = threadIdx.x;
    const int wv   = t >> 6;
    const int lane = t & 63;
    const int j    = t & 3;        // build: o-quad owned by this lane
    const int g    = t >> 2;       // build: cluster id, 0..255

    // XCD swizzle: 1280 % 8 == 0 -> bijective; same-c blocks share an XCD L2.
    const int bid = blockIdx.x;
    const int swz = (bid & 7) * (NCAP * (NB / TB) / 8) + (bid >> 3);
    const int c   = swz / (NB / TB);
    const int b0  = (swz % (NB / TB)) * TB;

    const int bl0 = lane & 1, bl1 = (lane >> 1) & 1,
              bl2 = (lane >> 2) & 1, bl3 = (lane >> 3) & 1;

    // 16B-slot index within a tb-plane (quad q of row n)
    auto slotof = [](int n, int q) { return 2 * n + (q ^ ((n >> 2) & 1)); };

    // iter-1 weighted sum partials, (tb0,tb1) packed; k = o-quad element
    v2f bs2[4] = {v2f{0.f,0.f}, v2f{0.f,0.f}, v2f{0.f,0.f}, v2f{0.f,0.f}};

    // ---- build: 4-lane cluster per n; lane j computes o-quad j ----
    auto build_round = [&](int n) {
        const float4* wp = reinterpret_cast<const float4*>(
            w + ((size_t)c * NN + n) * (KI * NO));
        v2f xs2[KI];   // (b0, b1) pairs
        {
            const float4* xp0 = reinterpret_cast<const float4*>(
                x + ((size_t)(b0 + 0) * NN + n) * KI);
            const float4* xp1 = reinterpret_cast<const float4*>(
                x + ((size_t)(b0 + 1) * NN + n) * KI);
            float4 a0 = xp0[0], a1 = xp0[1];   // bcast across cluster
            float4 c0 = xp1[0], c1 = xp1[1];
            xs2[0] = v2f{a0.x, c0.x}; xs2[1] = v2f{a0.y, c0.y};
            xs2[2] = v2f{a0.z, c0.z}; xs2[3] = v2f{a0.w, c0.w};
            xs2[4] = v2f{a1.x, c1.x}; xs2[5] = v2f{a1.y, c1.y};
            xs2[6] = v2f{a1.z, c1.z}; xs2[7] = v2f{a1.w, c1.w};
        }
        v2f acc2[4] = {v2f{0.f,0.f}, v2f{0.f,0.f}, v2f{0.f,0.f}, v2f{0.f,0.f}};
        #pragma unroll
        for (int i = 0; i < KI; ++i) {
            float4 wq = wp[i * 4 + j];   // dense 64B lines across wave
            acc2[0] = __builtin_elementwise_fma(xs2[i], v2f{wq.x, wq.x}, acc2[0]);
            acc2[1] = __builtin_elementwise_fma(xs2[i], v2f{wq.y, wq.y}, acc2[1]);
            acc2[2] = __builtin_elementwise_fma(xs2[i], v2f{wq.z, wq.z}, acc2[2]);
            acc2[3] = __builtin_elementwise_fma(xs2[i], v2f{wq.w, wq.w}, acc2[3]);
        }
        bs2[0] += acc2[0]; bs2[1] += acc2[1];
        bs2[2] += acc2[2]; bs2[3] += acc2[3];
        // lane j holds ops {4j..4j+3} = pairs {2j,2j+1} = 8B in quad j>>1
        const int q = j >> 1, h = j & 1;
        unsigned p0, p1, p2, p3;   // cvt_pk: lo16=src0, hi16=src1 (RNE)
        asm("v_cvt_pk_bf16_f32 %0, %1, %2"
            : "=v"(p0) : "v"(acc2[0].x), "v"(acc2[1].x));
        asm("v_cvt_pk_bf16_f32 %0, %1, %2"
            : "=v"(p1) : "v"(acc2[2].x), "v"(acc2[3].x));
        asm("v_cvt_pk_bf16_f32 %0, %1, %2"
            : "=v"(p2) : "v"(acc2[0].y), "v"(acc2[1].y));
        asm("v_cvt_pk_bf16_f32 %0, %1, %2"
            : "=v"(p3) : "v"(acc2[2].y), "v"(acc2[3].y));
        uint2 k0; k0.x = p0; k0.y = p1;
        uint2 k1; k1.x = p2; k1.y = p3;
        *reinterpret_cast<uint2*>(&s_pr[0 * (NN*8) + slotof(n, q) * 4 + h * 2]) = k0;
        *reinterpret_cast<uint2*>(&s_pr[1 * (NN*8) + slotof(n, q) * 4 + h * 2]) = k1;
    };
    #pragma unroll 1
    for (int r = 0; r < 4; ++r) build_round(r * 256 + g);
    if (g < 128) build_round(1024 + g);      // wave-uniform (t < 512)

    // reduce bs across the wave's 16 clusters (same j): lanes 0..3 write
    float bsr[TB][4];
    #pragma unroll
    for (int k = 0; k < 4; ++k) { bsr[0][k] = bs2[k].x; bsr[1][k] = bs2[k].y; }
    #pragma unroll
    for (int tb = 0; tb < TB; ++tb)
        #pragma unroll
        for (int k = 0; k < 4; ++k) {
            float s = bsr[tb][k];
            s += __shfl_xor(s, 4);  s += __shfl_xor(s, 8);
            s += __shfl_xor(s, 16); s += __shfl_xor(s, 32);
            bsr[tb][k] = s;
        }
    if (lane < 4) {
        #pragma unroll
        for (int tb = 0; tb < TB; ++tb) {
            s_red2[wv][tb][4*lane+0] = bsr[tb][0];
            s_red2[wv][tb][4*lane+1] = bsr[tb][1];
            s_red2[wv][tb][4*lane+2] = bsr[tb][2];
            s_red2[wv][tb][4*lane+3] = bsr[tb][3];
        }
    }
    __syncthreads();

    // ---- finalize: combine waves, softmax-normalize, squash ----
    auto finalize = [&](int iter) {
        if (t < TB * NO) {
            const int tb = t >> 4, oc = t & 15;
            float acc = 0.f, lt = 0.f;
            #pragma unroll
            for (int w2 = 0; w2 < NWV; ++w2) {
                acc += s_red2[w2][tb][oc];
                if (iter > 0) lt += s_ls[w2][tb];
            }
            if (iter == 0) lt = (float)NN;   // softmax(0) is uniform
            float s_o = acc / lt;
            float sq = s_o * s_o;
            sq += __shfl_xor(sq, 1); sq += __shfl_xor(sq, 2);
            sq += __shfl_xor(sq, 4); sq += __shfl_xor(sq, 8);
            float scale = sq / ((1.f + sq) * sqrtf(sq));
            float vo = s_o * scale;
            s_v[tb][oc] = vo;
            if (iter == NITER - 1)
                out[((size_t)c * NB + b0 + tb) * NO + oc] = vo;
        }
    };

    // consumption: thread owns n=t (and 1024+t if t<128) -> private logits;
    // delta + exp + weighted-sum fused in ONE pass over the bf16 priors.
    float logit[2][TB] = {{0.f,0.f},{0.f,0.f}};

    auto routing_pass = [&]() {
        #pragma unroll
        for (int tb = 0; tb < TB; ++tb) {
            v2f vv2[8];
            {
                const float4* vp = reinterpret_cast<const float4*>(&s_v[tb][0]);
                float4 a = vp[0], b = vp[1], cc = vp[2], d4 = vp[3];
                vv2[0] = v2f{a.x,  a.y};  vv2[1] = v2f{a.z,  a.w};
                vv2[2] = v2f{b.x,  b.y};  vv2[3] = v2f{b.z,  b.w};
                vv2[4] = v2f{cc.x, cc.y}; vv2[5] = v2f{cc.z, cc.w};
                vv2[6] = v2f{d4.x, d4.y}; vv2[7] = v2f{d4.z, d4.w};
            }
            v2f sp2[8];
            #pragma unroll
            for (int p = 0; p < 8; ++p) sp2[p] = v2f{0.f, 0.f};
            float lse = 0.f;
            #pragma unroll
            for (int rr = 0; rr < 2; ++rr) {
                if (rr == 1 && t >= 128) continue;   // wave-uniform
                const int n = rr * 1024 + t;
                const unsigned* base = &s_pr[tb * (NN * 8)];
                uint4 qa = *reinterpret_cast<const uint4*>(&base[slotof(n, 0) * 4]);
                uint4 qb = *reinterpret_cast<const uint4*>(&base[slotof(n, 1) * 4]);
                unsigned u[8] = {qa.x, qa.y, qa.z, qa.w, qb.x, qb.y, qb.z, qb.w};
                v2f row2[8];
                #pragma unroll
                for (int op = 0; op < 8; ++op) {
                    row2[op].x = __uint_as_float(u[op] << 16);
                    row2[op].y = __uint_as_float(u[op] & 0xffff0000u);
                }
                v2f d2 = v2f{0.f, 0.f};
                #pragma unroll
                for (int op = 0; op < 8; ++op)
                    d2 = __builtin_elementwise_fma(row2[op], vv2[op], d2);
                logit[rr][tb] += d2.x + d2.y;   // |logit| <~ 30: f32-safe
                float e = __expf(logit[rr][tb]);
                lse += e;
                v2f e2 = v2f{e, e};
                #pragma unroll
                for (int op = 0; op < 8; ++op)
                    sp2[op] = __builtin_elementwise_fma(e2, row2[op], sp2[op]);
            }
            // exp-sum: full-wave butterfly
            float s = lse;
            s += __shfl_xor(s, 1);  s += __shfl_xor(s, 2);
            s += __shfl_xor(s, 4);  s += __shfl_xor(s, 8);
            s += __shfl_xor(s, 16); s += __shfl_xor(s, 32);
            if (lane == 0) s_ls[wv][tb] = s;
            // comp-halving fold: 16 comps over 16-lane groups in 15 shuffles
            float g8[8];
            #pragma unroll
            for (int r = 0; r < 8; ++r) {
                float keep = bl0 ? sp2[r].y : sp2[r].x;
                float send = bl0 ? sp2[r].x : sp2[r].y;
                g8[r] = keep + __shfl_xor(send, 1);
            }
            float g4[4];
            #pragma unroll
            for (int r = 0; r < 4; ++r) {
                float keep = bl1 ? g8[2*r+1] : g8[2*r];
                float send = bl1 ? g8[2*r]   : g8[2*r+1];
                g4[r] = keep + __shfl_xor(send, 2);
            }
            float g2[2];
            #pragma unroll
            for (int r = 0; r < 2; ++r) {
                float keep = bl2 ? g4[2*r+1] : g4[2*r];
                float send = bl2 ? g4[2*r]   : g4[2*r+1];
                g2[r] = keep + __shfl_xor(send, 4);
            }
            float g1;
            {
                float keep = bl3 ? g2[1] : g2[0];
                float send = bl3 ? g2[0] : g2[1];
                g1 = keep + __shfl_xor(send, 8);
            }
            g1 += __shfl_xor(g1, 16);
            g1 += __shfl_xor(g1, 32);
            if (lane < NO) s_red2[wv][tb][lane] = g1;
        }
    };

    finalize(0);          // v1 from uniform probs (build-side f32 sums)
    __syncthreads();
    routing_pass();       // logits += prior.v1; sums for iter 2
    __syncthreads();
    finalize(1);          // v2
    __syncthreads();
    routing_pass();       // logits += prior.v2; sums for iter 3
    __syncthreads();
    finalize(2);          // v3 -> out
}

extern "C" void kernel_launch(void* const* d_in, const int* in_sizes, int n_in,
                              void* d_out, int out_size, void* d_ws, size_t ws_size,
                              hipStream_t stream) {
    const float* x = (const float*)d_in[0];
    const float* w = (const float*)d_in[1];
    float* out = (float*)d_out;
    capsule_kernel<<<dim3(NCAP * (NB / TB)), dim3(NT), 0, stream>>>(x, w, out);
}

// Round 15
// 62.661 us; speedup vs baseline: 1.2450x; 1.2450x over previous
//
#include <hip/hip_runtime.h>

#define NCAP 10     // capsule classes c
#define NB   256    // batch b
#define NN   1152   // route nodes n
#define KI   8      // input dim i
#define NO   16     // output dim o
#define NT   1024   // threads per block (16 waves)
#define NWV  16
#define TB   2      // batches per block
#define NITER 3

typedef float v2f __attribute__((ext_vector_type(2)));

// Round-13 build (proven: 58.5 us, VGPR 32, zero spill) + pk-f32 ONLY in the
// routing pass with a lean register plan (r2[8] unpacked once, sp2[8] packed).
// Round-14 lesson: packing BOTH phases spilled under the 64-reg clamp
// (WRITE 160KB -> 25.8MB); build stays scalar.
__global__ __launch_bounds__(NT, 8) void capsule_kernel(
    const float* __restrict__ x,    // [256,1152,8]
    const float* __restrict__ w,    // [10,1152,8,16]
    float* __restrict__ out)        // [10,256,16]
{
    __shared__ unsigned s_pr[TB * NN * 8];    // 72 KB bf16-pair priors
    __shared__ float s_red2[NWV][TB][NO];     // per-wave comp partials
    __shared__ float s_ls[NWV][TB];           // per-wave exp-sum partials
    __shared__ float s_v[TB][NO];             // squashed v broadcast

    const int t    = threadIdx.x;
    const int wv   = t >> 6;
    const int lane = t & 63;
    const int j    = t & 3;        // build: o-quad owned by this lane
    const int g    = t >> 2;       // build: cluster id, 0..255

    // XCD swizzle: 1280 % 8 == 0 -> bijective; same-c blocks share an XCD L2.
    const int bid = blockIdx.x;
    const int swz = (bid & 7) * (NCAP * (NB / TB) / 8) + (bid >> 3);
    const int c   = swz / (NB / TB);
    const int b0  = (swz % (NB / TB)) * TB;

    const int bl0 = lane & 1, bl1 = (lane >> 1) & 1,
              bl2 = (lane >> 2) & 1, bl3 = (lane >> 3) & 1;

    // 16B-slot index within a tb-plane (quad q of row n)
    auto slotof = [](int n, int q) { return 2 * n + (q ^ ((n >> 2) & 1)); };

    // iter-1 weighted sum (softmax(0) uniform) accumulated in f32 during build
    float bs[TB][4] = {{0.f,0.f,0.f,0.f},{0.f,0.f,0.f,0.f}};

    // ---- build: 4-lane cluster per n; lane j computes o-quad j (scalar,
    // byte-identical to round 13) ----
    auto build_round = [&](int n) {
        const float4* wp = reinterpret_cast<const float4*>(
            w + ((size_t)c * NN + n) * (KI * NO));
        float xs[TB][KI];
        #pragma unroll
        for (int tb = 0; tb < TB; ++tb) {
            const float4* xp = reinterpret_cast<const float4*>(
                x + ((size_t)(b0 + tb) * NN + n) * KI);
            float4 a = xp[0], b = xp[1];   // same addr across cluster -> bcast
            xs[tb][0]=a.x; xs[tb][1]=a.y; xs[tb][2]=a.z; xs[tb][3]=a.w;
            xs[tb][4]=b.x; xs[tb][5]=b.y; xs[tb][6]=b.z; xs[tb][7]=b.w;
        }
        float acc[TB][4] = {{0.f,0.f,0.f,0.f},{0.f,0.f,0.f,0.f}};
        #pragma unroll
        for (int i = 0; i < KI; ++i) {
            float4 wq = wp[i * 4 + j];
            #pragma unroll
            for (int tb = 0; tb < TB; ++tb) {
                acc[tb][0] = fmaf(xs[tb][i], wq.x, acc[tb][0]);
                acc[tb][1] = fmaf(xs[tb][i], wq.y, acc[tb][1]);
                acc[tb][2] = fmaf(xs[tb][i], wq.z, acc[tb][2]);
                acc[tb][3] = fmaf(xs[tb][i], wq.w, acc[tb][3]);
            }
        }
        // lane j holds ops {4j..4j+3} = pairs {2j, 2j+1} = 8B in quad j>>1
        const int q = j >> 1, h = j & 1;
        #pragma unroll
        for (int tb = 0; tb < TB; ++tb) {
            bs[tb][0] += acc[tb][0]; bs[tb][1] += acc[tb][1];
            bs[tb][2] += acc[tb][2]; bs[tb][3] += acc[tb][3];
            unsigned p0, p1;   // pair: even op lo16, odd op hi16 (RNE)
            asm("v_cvt_pk_bf16_f32 %0, %1, %2"
                : "=v"(p0) : "v"(acc[tb][0]), "v"(acc[tb][1]));
            asm("v_cvt_pk_bf16_f32 %0, %1, %2"
                : "=v"(p1) : "v"(acc[tb][2]), "v"(acc[tb][3]));
            uint2 pk; pk.x = p0; pk.y = p1;
            *reinterpret_cast<uint2*>(
                &s_pr[tb * (NN * 8) + slotof(n, q) * 4 + h * 2]) = pk;
        }
    };
    #pragma unroll 1
    for (int r = 0; r < 4; ++r) build_round(r * 256 + g);
    if (g < 128) build_round(1024 + g);      // wave-uniform (t < 512)

    // reduce bs across the wave's 16 clusters (same j): lanes 0..3 write
    #pragma unroll
    for (int tb = 0; tb < TB; ++tb)
        #pragma unroll
        for (int k = 0; k < 4; ++k) {
            float s = bs[tb][k];
            s += __shfl_xor(s, 4);  s += __shfl_xor(s, 8);
            s += __shfl_xor(s, 16); s += __shfl_xor(s, 32);
            bs[tb][k] = s;
        }
    if (lane < 4) {
        #pragma unroll
        for (int tb = 0; tb < TB; ++tb) {
            s_red2[wv][tb][4*lane+0] = bs[tb][0];
            s_red2[wv][tb][4*lane+1] = bs[tb][1];
            s_red2[wv][tb][4*lane+2] = bs[tb][2];
            s_red2[wv][tb][4*lane+3] = bs[tb][3];
        }
    }
    __syncthreads();

    // ---- finalize: combine waves, softmax-normalize, squash ----
    auto finalize = [&](int iter) {
        if (t < TB * NO) {
            const int tb = t >> 4, oc = t & 15;
            float acc = 0.f, lt = 0.f;
            #pragma unroll
            for (int w2 = 0; w2 < NWV; ++w2) {
                acc += s_red2[w2][tb][oc];
                if (iter > 0) lt += s_ls[w2][tb];
            }
            if (iter == 0) lt = (float)NN;   // softmax(0) is uniform
            float s_o = acc / lt;
            float sq = s_o * s_o;
            sq += __shfl_xor(sq, 1); sq += __shfl_xor(sq, 2);
            sq += __shfl_xor(sq, 4); sq += __shfl_xor(sq, 8);
            float scale = sq / ((1.f + sq) * sqrtf(sq));
            float vo = s_o * scale;
            s_v[tb][oc] = vo;
            if (iter == NITER - 1)
                out[((size_t)c * NB + b0 + tb) * NO + oc] = vo;
        }
    };

    // consumption: thread owns n=t (and 1024+t if t<128) -> private logits;
    // delta + exp + weighted-sum fused in ONE pk-f32 pass over bf16 priors.
    float logit[2][TB] = {{0.f,0.f},{0.f,0.f}};

    auto routing_pass = [&]() {
        #pragma unroll
        for (int tb = 0; tb < TB; ++tb) {
            v2f vv2[8];
            {
                const float4* vp = reinterpret_cast<const float4*>(&s_v[tb][0]);
                float4 a = vp[0], b = vp[1], cc = vp[2], d4 = vp[3];
                vv2[0] = v2f{a.x,  a.y};  vv2[1] = v2f{a.z,  a.w};
                vv2[2] = v2f{b.x,  b.y};  vv2[3] = v2f{b.z,  b.w};
                vv2[4] = v2f{cc.x, cc.y}; vv2[5] = v2f{cc.z, cc.w};
                vv2[6] = v2f{d4.x, d4.y}; vv2[7] = v2f{d4.z, d4.w};
            }
            v2f sp2[8];
            #pragma unroll
            for (int p = 0; p < 8; ++p) sp2[p] = v2f{0.f, 0.f};
            float lse = 0.f;
            #pragma unroll
            for (int rr = 0; rr < 2; ++rr) {
                if (rr == 1 && t >= 128) continue;   // wave-uniform
                const int n = rr * 1024 + t;
                const unsigned* base = &s_pr[tb * (NN * 8)];
                uint4 qa = *reinterpret_cast<const uint4*>(&base[slotof(n, 0) * 4]);
                uint4 qb = *reinterpret_cast<const uint4*>(&base[slotof(n, 1) * 4]);
                unsigned u[8] = {qa.x, qa.y, qa.z, qa.w, qb.x, qb.y, qb.z, qb.w};
                v2f r2[8];                 // unpack ONCE, reuse in both chains
                #pragma unroll
                for (int op = 0; op < 8; ++op) {
                    r2[op].x = __uint_as_float(u[op] << 16);
                    r2[op].y = __uint_as_float(u[op] & 0xffff0000u);
                }
                v2f d2 = v2f{0.f, 0.f};
                #pragma unroll
                for (int op = 0; op < 8; ++op)
                    d2 = __builtin_elementwise_fma(r2[op], vv2[op], d2);
                logit[rr][tb] += d2.x + d2.y;   // |logit| <~ 30: f32-safe
                float e = __expf(logit[rr][tb]);
                lse += e;
                v2f e2 = v2f{e, e};
                #pragma unroll
                for (int op = 0; op < 8; ++op)
                    sp2[op] = __builtin_elementwise_fma(e2, r2[op], sp2[op]);
            }
            // exp-sum: full-wave butterfly
            float s = lse;
            s += __shfl_xor(s, 1);  s += __shfl_xor(s, 2);
            s += __shfl_xor(s, 4);  s += __shfl_xor(s, 8);
            s += __shfl_xor(s, 16); s += __shfl_xor(s, 32);
            if (lane == 0) s_ls[wv][tb] = s;
            // comp-halving fold: stage 1 consumes sp2 halves directly
            float g8[8];
            #pragma unroll
            for (int r = 0; r < 8; ++r) {
                float keep = bl0 ? sp2[r].y : sp2[r].x;
                float send = bl0 ? sp2[r].x : sp2[r].y;
                g8[r] = keep + __shfl_xor(send, 1);
            }
            float g4[4];
            #pragma unroll
            for (int r = 0; r < 4; ++r) {
                float keep = bl1 ? g8[2*r+1] : g8[2*r];
                float send = bl1 ? g8[2*r]   : g8[2*r+1];
                g4[r] = keep + __shfl_xor(send, 2);
            }
            float g2[2];
            #pragma unroll
            for (int r = 0; r < 2; ++r) {
                float keep = bl2 ? g4[2*r+1] : g4[2*r];
                float send = bl2 ? g4[2*r]   : g4[2*r+1];
                g2[r] = keep + __shfl_xor(send, 4);
            }
            float g1;
            {
                float keep = bl3 ? g2[1] : g2[0];
                float send = bl3 ? g2[0] : g2[1];
                g1 = keep + __shfl_xor(send, 8);
            }
            g1 += __shfl_xor(g1, 16);
            g1 += __shfl_xor(g1, 32);
            if (lane < NO) s_red2[wv][tb][lane] = g1;
        }
    };

    finalize(0);          // v1 from uniform probs (build-side f32 sums)
    __syncthreads();
    routing_pass();       // logits += prior.v1; sums for iter 2
    __syncthreads();
    finalize(1);          // v2
    __syncthreads();
    routing_pass();       // logits += prior.v2; sums for iter 3
    __syncthreads();
    finalize(2);          // v3 -> out
}

extern "C" void kernel_launch(void* const* d_in, const int* in_sizes, int n_in,
                              void* d_out, int out_size, void* d_ws, size_t ws_size,
                              hipStream_t stream) {
    const float* x = (const float*)d_in[0];
    const float* w = (const float*)d_in[1];
    float* out = (float*)d_out;
    capsule_kernel<<<dim3(NCAP * (NB / TB)), dim3(NT), 0, stream>>>(x, w, out);
}

// Round 16
// 57.639 us; speedup vs baseline: 1.3535x; 1.0871x over previous
//
#include <hip/hip_runtime.h>

#define NCAP 10     // capsule classes c
#define NB   256    // batch b
#define NN   1152   // route nodes n
#define KI   8      // input dim i
#define NO   16     // output dim o
#define NT   1024   // threads per block (16 waves: 8 build + 8 route)
#define TB   2      // batches per problem
#define NPROB 5     // problems per block (1280 / 256 blocks)
#define NBLK 256    // grid = 1 block per CU

typedef float v2f __attribute__((ext_vector_type(2)));

// Producer/consumer pipeline: waves 0-7 build problem k's bf16 priors into
// s_pr[k&1] while waves 8-15 route problem k-1 from s_pr[(k-1)&1]. Fixes
// round-13's structural flaw: co-resident blocks ran the SAME phase in
// lockstep, so build (mem-heavy) and route (VALU/DS-heavy) never overlapped.
// 128-reg budget (1 block/CU) removes the spill wall of rounds 14/15.
__global__ __launch_bounds__(NT, 4) void capsule_kernel(
    const float* __restrict__ x,    // [256,1152,8]
    const float* __restrict__ w,    // [10,1152,8,16]
    float* __restrict__ out)        // [10,256,16]
{
    __shared__ unsigned s_pr[2][TB * NN * 8];   // 2 x 72 KB priors (parity)
    __shared__ float s_bsw[8][TB][NO];          // build-wave iter-1 partials
    __shared__ float s_rp[2][8][TB][NO];        // route partials (iter parity)
    __shared__ float s_lse[2][8][TB];           // route exp-sums (iter parity)

    const int t = threadIdx.x, wv = t >> 6, lane = t & 63, bid = blockIdx.x;
    const int j = t & 3, g2 = t >> 2;           // build: o-quad, cluster 0..127
    const int rt = t - 512, rwv = wv - 8;       // route ids
    const int tb2 = (lane >> 4) & 1, oc = lane & 15;
    const int bl0 = lane & 1, bl1 = (lane >> 1) & 1,
              bl2v = (lane >> 2) & 1, bl3 = (lane >> 3) & 1;

    auto slotof = [](int n, int q) { return 2 * n + (q ^ ((n >> 2) & 1)); };
    auto squash = [&](float s_o) {
        float sq = s_o * s_o;
        sq += __shfl_xor(sq, 1); sq += __shfl_xor(sq, 2);
        sq += __shfl_xor(sq, 4); sq += __shfl_xor(sq, 8);
        return s_o * (sq / ((1.f + sq) * sqrtf(sq)));
    };

    #pragma unroll 1
    for (int k = 0; k <= NPROB; ++k) {
        const int parB = k & 1, parR = parB ^ 1;
        const bool do_build = (k < NPROB), do_route = (k >= 1);
        // problem->(c,b0): P&7 = bid&7 keeps same-c problems on one XCD
        const int Pb = k * NBLK + bid;
        const int swzB = (Pb & 7) * 160 + (Pb >> 3);
        const int cB = swzB >> 7, b0B = (swzB & 127) * 2;
        const int Pr = (k - 1) * NBLK + bid;
        const int swzR = (Pr & 7) * 160 + (Pr >> 3);
        const int cR = swzR >> 7, b0R = (swzR & 127) * 2;

        float bs[TB][4] = {{0.f,0.f,0.f,0.f},{0.f,0.f,0.f,0.f}};
        float logit[3][TB];
        float vo = 0.f;

        auto build_round = [&](int n) {
            const float4* wp = reinterpret_cast<const float4*>(
                w + ((size_t)cB * NN + n) * (KI * NO));
            float xs[TB][KI];
            #pragma unroll
            for (int tb = 0; tb < TB; ++tb) {
                const float4* xp = reinterpret_cast<const float4*>(
                    x + ((size_t)(b0B + tb) * NN + n) * KI);
                float4 a = xp[0], b = xp[1];    // bcast across cluster
                xs[tb][0]=a.x; xs[tb][1]=a.y; xs[tb][2]=a.z; xs[tb][3]=a.w;
                xs[tb][4]=b.x; xs[tb][5]=b.y; xs[tb][6]=b.z; xs[tb][7]=b.w;
            }
            float4 wq[KI];                       // 8 loads in flight (128-reg ok)
            #pragma unroll
            for (int i = 0; i < KI; ++i) wq[i] = wp[i * 4 + j];
            float acc[TB][4] = {{0.f,0.f,0.f,0.f},{0.f,0.f,0.f,0.f}};
            #pragma unroll
            for (int i = 0; i < KI; ++i)
                #pragma unroll
                for (int tb = 0; tb < TB; ++tb) {
                    acc[tb][0] = fmaf(xs[tb][i], wq[i].x, acc[tb][0]);
                    acc[tb][1] = fmaf(xs[tb][i], wq[i].y, acc[tb][1]);
                    acc[tb][2] = fmaf(xs[tb][i], wq[i].z, acc[tb][2]);
                    acc[tb][3] = fmaf(xs[tb][i], wq[i].w, acc[tb][3]);
                }
            const int q = j >> 1, h = j & 1;
            #pragma unroll
            for (int tb = 0; tb < TB; ++tb) {
                bs[tb][0] += acc[tb][0]; bs[tb][1] += acc[tb][1];
                bs[tb][2] += acc[tb][2]; bs[tb][3] += acc[tb][3];
                unsigned p0, p1;
                asm("v_cvt_pk_bf16_f32 %0, %1, %2"
                    : "=v"(p0) : "v"(acc[tb][0]), "v"(acc[tb][1]));
                asm("v_cvt_pk_bf16_f32 %0, %1, %2"
                    : "=v"(p1) : "v"(acc[tb][2]), "v"(acc[tb][3]));
                uint2 pk2; pk2.x = p0; pk2.y = p1;
                *reinterpret_cast<uint2*>(
                    &s_pr[parB][tb * (NN*8) + slotof(n, q) * 4 + h * 2]) = pk2;
            }
        };

        auto route_iter = [&](bool first, int wpar) {
            #pragma unroll
            for (int tb = 0; tb < TB; ++tb) {
                v2f vv2[8];
                #pragma unroll
                for (int o2 = 0; o2 < 8; ++o2) {   // in-wave v broadcast
                    vv2[o2].x = __shfl(vo, tb * 16 + 2 * o2);
                    vv2[o2].y = __shfl(vo, tb * 16 + 2 * o2 + 1);
                }
                v2f sp2[8];
                #pragma unroll
                for (int p = 0; p < 8; ++p) sp2[p] = v2f{0.f, 0.f};
                float lse = 0.f;
                #pragma unroll
                for (int row = 0; row < 3; ++row) {
                    if (row < 2 || rt < 128) {     // waves 8,9 own the tail
                        const int n = row * 512 + rt;
                        const unsigned* base = &s_pr[parR][tb * (NN * 8)];
                        uint4 qa = *reinterpret_cast<const uint4*>(&base[slotof(n, 0) * 4]);
                        uint4 qb = *reinterpret_cast<const uint4*>(&base[slotof(n, 1) * 4]);
                        unsigned u[8] = {qa.x, qa.y, qa.z, qa.w, qb.x, qb.y, qb.z, qb.w};
                        v2f r2[8];
                        #pragma unroll
                        for (int op = 0; op < 8; ++op) {
                            r2[op].x = __uint_as_float(u[op] << 16);
                            r2[op].y = __uint_as_float(u[op] & 0xffff0000u);
                        }
                        v2f d2 = v2f{0.f, 0.f};
                        #pragma unroll
                        for (int op = 0; op < 8; ++op)
                            d2 = __builtin_elementwise_fma(r2[op], vv2[op], d2);
                        float lg = d2.x + d2.y;
                        if (!first) lg += logit[row][tb];
                        logit[row][tb] = lg;       // |logit| <~30: f32-safe
                        float e = __expf(lg);
                        lse += e;
                        v2f e2 = v2f{e, e};
                        #pragma unroll
                        for (int op = 0; op < 8; ++op)
                            sp2[op] = __builtin_elementwise_fma(e2, r2[op], sp2[op]);
                    }
                }
                float s = lse;
                s += __shfl_xor(s, 1);  s += __shfl_xor(s, 2);
                s += __shfl_xor(s, 4);  s += __shfl_xor(s, 8);
                s += __shfl_xor(s, 16); s += __shfl_xor(s, 32);
                if (lane == 0) s_lse[wpar][rwv][tb] = s;
                float g8[8];
                #pragma unroll
                for (int r = 0; r < 8; ++r) {
                    float keep = bl0 ? sp2[r].y : sp2[r].x;
                    float send = bl0 ? sp2[r].x : sp2[r].y;
                    g8[r] = keep + __shfl_xor(send, 1);
                }
                float g4[4];
                #pragma unroll
                for (int r = 0; r < 4; ++r) {
                    float keep = bl1 ? g8[2*r+1] : g8[2*r];
                    float send = bl1 ? g8[2*r]   : g8[2*r+1];
                    g4[r] = keep + __shfl_xor(send, 2);
                }
                float g2x[2];
                #pragma unroll
                for (int r = 0; r < 2; ++r) {
                    float keep = bl2v ? g4[2*r+1] : g4[2*r];
                    float send = bl2v ? g4[2*r]   : g4[2*r+1];
                    g2x[r] = keep + __shfl_xor(send, 4);
                }
                float g1;
                {
                    float keep = bl3 ? g2x[1] : g2x[0];
                    float send = bl3 ? g2x[0] : g2x[1];
                    g1 = keep + __shfl_xor(send, 8);
                }
                g1 += __shfl_xor(g1, 16);
                g1 += __shfl_xor(g1, 32);
                if (lane < NO) s_rp[wpar][rwv][tb][lane] = g1;
            }
        };

        // ---------------- STAGE 1: build r0-2 | fin0 + iter1 ----------------
        if (t < 512) {
            if (do_build) { build_round(g2); build_round(128 + g2); build_round(256 + g2); }
        } else if (do_route) {
            float acc = 0.f;
            #pragma unroll
            for (int w2 = 0; w2 < 8; ++w2) acc += s_bsw[w2][tb2][oc];
            vo = squash(acc / (float)NN);       // softmax(0) is uniform
            route_iter(true, 1);
        }
        __syncthreads();
        // ---------------- STAGE 2: build r3-5 | fin1 + iter2 ----------------
        if (t < 512) {
            if (do_build) { build_round(384 + g2); build_round(512 + g2); build_round(640 + g2); }
        } else if (do_route) {
            float acc = 0.f, lt = 0.f;
            #pragma unroll
            for (int w2 = 0; w2 < 8; ++w2) {
                acc += s_rp[1][w2][tb2][oc]; lt += s_lse[1][w2][tb2];
            }
            vo = squash(acc / lt);
            route_iter(false, 0);
        }
        __syncthreads();
        // ---------------- STAGE 3: build r6-8 + bs | fin2 -> out ------------
        if (t < 512) {
            if (do_build) {
                build_round(768 + g2); build_round(896 + g2); build_round(1024 + g2);
                #pragma unroll
                for (int tb = 0; tb < TB; ++tb)
                    #pragma unroll
                    for (int kk = 0; kk < 4; ++kk) {
                        float s = bs[tb][kk];
                        s += __shfl_xor(s, 4);  s += __shfl_xor(s, 8);
                        s += __shfl_xor(s, 16); s += __shfl_xor(s, 32);
                        bs[tb][kk] = s;
                    }
                if (lane < 4) {
                    #pragma unroll
                    for (int tb = 0; tb < TB; ++tb) {
                        s_bsw[wv][tb][4*lane+0] = bs[tb][0];
                        s_bsw[wv][tb][4*lane+1] = bs[tb][1];
                        s_bsw[wv][tb][4*lane+2] = bs[tb][2];
                        s_bsw[wv][tb][4*lane+3] = bs[tb][3];
                    }
                }
            }
        } else if (do_route) {
            float acc = 0.f, lt = 0.f;
            #pragma unroll
            for (int w2 = 0; w2 < 8; ++w2) {
                acc += s_rp[0][w2][tb2][oc]; lt += s_lse[0][w2][tb2];
            }
            vo = squash(acc / lt);
            if (wv == 8 && lane < 32)
                out[((size_t)cR * NB + b0R + tb2) * NO + oc] = vo;
        }
        __syncthreads();
    }
}

extern "C" void kernel_launch(void* const* d_in, const int* in_sizes, int n_in,
                              void* d_out, int out_size, void* d_ws, size_t ws_size,
                              hipStream_t stream) {
    const float* x = (const float*)d_in[0];
    const float* w = (const float*)d_in[1];
    float* out = (float*)d_out;
    capsule_kernel<<<dim3(NBLK), dim3(NT), 0, stream>>>(x, w, out);
}